// Round 2
// baseline (3090.052 us; speedup 1.0000x reference)
//
#include <hip/hip_runtime.h>
#include <cstdint>

// GptOssExpertsLinear: E=16, H=D=2880, T=2048.
// out[t,h] = sum_e rw[t,e] * ( act(x@Wg[e]+bg, x@Wu[e]+bu) @ Wd[e] + bd )
// act: gate=min(g,7); up=clip(u,-7,7); inter=(up+1)*gate*sigmoid(1.702*gate)
// Correctness-first structure: bf16 MFMA 16x16x32, fp32 accum, plain LDS
// staging (reg-staged, padded strides, no global_load_lds / tr-reads / asm).

#define ALPHA 1.702f
#define LIMIT 7.0f

static constexpr int E = 16;
static constexpr int H = 2880;
static constexpr int D = 2880;
static constexpr int T = 2048;

// LDS strides (in bf16 elements)
static constexpr int LDA = 72;  // A tile [128][64], 144B rows: b128-aligned, 2-way banks (free)
static constexpr int LDB = 66;  // B^T tile [96][64], 132B rows: 33 words == 1 mod 32 -> conflict-free

typedef float        f32x4  __attribute__((ext_vector_type(4)));
typedef short        bf16x8 __attribute__((ext_vector_type(8)));
typedef unsigned int u32x4  __attribute__((ext_vector_type(4)));

#define MFMA_BF16(a,b,c) __builtin_amdgcn_mfma_f32_16x16x32_bf16((a),(b),(c),0,0,0)

// fp32 -> bf16 round-to-nearest-even (finite inputs)
__device__ __forceinline__ unsigned short f2bf(float f){
  unsigned u = __builtin_bit_cast(unsigned, f);
  u += 0x7fffu + ((u >> 16) & 1u);
  return (unsigned short)(u >> 16);
}
__device__ __forceinline__ unsigned pack2(float a, float b){
  return (unsigned)f2bf(a) | ((unsigned)f2bf(b) << 16);
}

// x fp32 -> bf16, 8 elems/thread
__global__ void cvt_kernel(const float* __restrict__ in, unsigned short* __restrict__ ob, int n8){
  int i = blockIdx.x * 256 + threadIdx.x;
  if (i < n8){
    float4 a = ((const float4*)in)[2*i];
    float4 b = ((const float4*)in)[2*i+1];
    uint4 o;
    o.x = pack2(a.x, a.y); o.y = pack2(a.z, a.w);
    o.z = pack2(b.x, b.y); o.w = pack2(b.z, b.w);
    ((uint4*)ob)[i] = o;
  }
}

// read one MFMA B fragment (8 bf16 along k) from the B^T tile
__device__ __forceinline__ bf16x8 read_bfrag(const short* Bs, int row, int c){
  const unsigned* p = (const unsigned*)&Bs[row*LDB + c*8]; // 4B aligned
  u32x4 u; u[0]=p[0]; u[1]=p[1]; u[2]=p[2]; u[3]=p[3];
  return __builtin_bit_cast(bf16x8, u);
}

// ---------------- gate+up fused GEMM + activation ----------------
// grid (T/128, D/96, ec); block 256 = 4 waves (2m x 2n); wave tile 64x48.
__global__ __launch_bounds__(256, 2) void gateup_kernel(
    const unsigned short* __restrict__ xb,   // [T][H] bf16
    const float* __restrict__ Wg, const float* __restrict__ bg,
    const float* __restrict__ Wu, const float* __restrict__ bu,
    unsigned short* __restrict__ inter,      // [ec][T][D] bf16
    int e0)
{
  __shared__ short As [128*LDA];
  __shared__ short Bgs[96*LDB];
  __shared__ short Bus[96*LDB];

  const int t    = threadIdx.x;
  const int lane = t & 63;
  const int wv   = t >> 6;
  const int wm   = wv >> 1, wn = wv & 1;
  const int trow0 = blockIdx.x * 128;
  const int ncol0 = blockIdx.y * 96;
  const int ez    = blockIdx.z;
  const int e     = e0 + ez;

  const float* wgp = Wg + (size_t)e * H * D;
  const float* wup = Wu + (size_t)e * H * D;

  f32x4 accg[4][3], accu[4][3];
  #pragma unroll
  for (int i = 0; i < 4; ++i)
    #pragma unroll
    for (int j = 0; j < 3; ++j){
      accg[i][j] = (f32x4){0.f,0.f,0.f,0.f};
      accu[i][j] = (f32x4){0.f,0.f,0.f,0.f};
    }

  for (int kt = 0; kt < H/64; ++kt){
    // A: 128 rows x 64 k, 16B per task, coalesced (8 threads per row)
    #pragma unroll
    for (int i = 0; i < 4; ++i){
      int task = i*256 + t;
      int row = task >> 3, ch = task & 7;
      *(bf16x8*)&As[row*LDA + ch*8] =
          *(const bf16x8*)(xb + (size_t)(trow0 + row)*H + kt*64 + ch*8);
    }
    // B: W[k][n] fp32 -> LDS B^T[n][k] bf16. 24 n-quads x 64 k rows.
    #pragma unroll
    for (int i = 0; i < 6; ++i){
      int task = i*256 + t;
      int n4 = task % 24, kr = task / 24;
      size_t go = (size_t)(kt*64 + kr)*D + (ncol0 + n4*4);
      float4 g = *(const float4*)(wgp + go);
      float4 u = *(const float4*)(wup + go);
      int rb = n4*4;
      Bgs[(rb+0)*LDB + kr] = f2bf(g.x);
      Bgs[(rb+1)*LDB + kr] = f2bf(g.y);
      Bgs[(rb+2)*LDB + kr] = f2bf(g.z);
      Bgs[(rb+3)*LDB + kr] = f2bf(g.w);
      Bus[(rb+0)*LDB + kr] = f2bf(u.x);
      Bus[(rb+1)*LDB + kr] = f2bf(u.y);
      Bus[(rb+2)*LDB + kr] = f2bf(u.z);
      Bus[(rb+3)*LDB + kr] = f2bf(u.w);
    }
    __syncthreads();
    #pragma unroll
    for (int kk = 0; kk < 2; ++kk){
      bf16x8 af[4];
      #pragma unroll
      for (int mi = 0; mi < 4; ++mi){
        int row = wm*64 + mi*16 + (lane & 15);
        af[mi] = *(const bf16x8*)&As[row*LDA + (kk*4 + (lane>>4))*8];
      }
      bf16x8 fg[3], fu[3];
      #pragma unroll
      for (int ni = 0; ni < 3; ++ni){
        int row = (wn*3 + ni)*16 + (lane & 15);
        int c   = kk*4 + (lane>>4);
        fg[ni] = read_bfrag(Bgs, row, c);
        fu[ni] = read_bfrag(Bus, row, c);
      }
      #pragma unroll
      for (int ni = 0; ni < 3; ++ni)
        #pragma unroll
        for (int mi = 0; mi < 4; ++mi){
          accg[mi][ni] = MFMA_BF16(af[mi], fg[ni], accg[mi][ni]);
          accu[mi][ni] = MFMA_BF16(af[mi], fu[ni], accu[mi][ni]);
        }
    }
    __syncthreads();
  }

  // epilogue: bias + clamp + glu -> inter bf16
  const float* bgp = bg + (size_t)e * D;
  const float* bup = bu + (size_t)e * D;
  unsigned short* ip = inter + (size_t)ez * T * D;
  #pragma unroll
  for (int ni = 0; ni < 3; ++ni){
    int d = ncol0 + wn*48 + ni*16 + (lane & 15);
    float bgv = bgp[d], buv = bup[d];
    #pragma unroll
    for (int mi = 0; mi < 4; ++mi){
      #pragma unroll
      for (int r = 0; r < 4; ++r){
        int trw = trow0 + wm*64 + mi*16 + (lane >> 4)*4 + r;
        float g = accg[mi][ni][r] + bgv;
        float u = accu[mi][ni][r] + buv;
        g = fminf(g, LIMIT);
        u = fminf(fmaxf(u, -LIMIT), LIMIT);
        float glu = g / (1.f + __expf(-ALPHA * g));
        ip[(size_t)trw * D + d] = f2bf((u + 1.f) * glu);
      }
    }
  }
}

// ---------------- down GEMM + routing-weighted accumulate ----------------
// grid (T/128, H/96); block loops over ec experts; out tile owned exclusively.
__global__ __launch_bounds__(256, 2) void down_kernel(
    const unsigned short* __restrict__ inter, // [ec][T][D] bf16
    const float* __restrict__ Wd, const float* __restrict__ bd,
    const float* __restrict__ rw,             // [T][E]
    float* __restrict__ out,                  // [T][H]
    int e0, int ec)
{
  __shared__ short As[128*LDA];
  __shared__ short Bs[96*LDB];

  const int t    = threadIdx.x;
  const int lane = t & 63;
  const int wv   = t >> 6;
  const int wm   = wv >> 1, wn = wv & 1;
  const int trow0 = blockIdx.x * 128;
  const int ncol0 = blockIdx.y * 96;

  f32x4 oacc[4][3];
  #pragma unroll
  for (int i = 0; i < 4; ++i)
    #pragma unroll
    for (int j = 0; j < 3; ++j) oacc[i][j] = (f32x4){0.f,0.f,0.f,0.f};

  #pragma unroll 1
  for (int ee = 0; ee < ec; ++ee){
    const int e = e0 + ee;
    const float* wdp = Wd + (size_t)e * D * H;
    const unsigned short* ap = inter + (size_t)ee * T * D;

    f32x4 acc[4][3];
    #pragma unroll
    for (int i = 0; i < 4; ++i)
      #pragma unroll
      for (int j = 0; j < 3; ++j) acc[i][j] = (f32x4){0.f,0.f,0.f,0.f};

    for (int kt = 0; kt < D/64; ++kt){
      #pragma unroll
      for (int i = 0; i < 4; ++i){
        int task = i*256 + t;
        int row = task >> 3, ch = task & 7;
        *(bf16x8*)&As[row*LDA + ch*8] =
            *(const bf16x8*)(ap + (size_t)(trow0 + row)*D + kt*64 + ch*8);
      }
      #pragma unroll
      for (int i = 0; i < 6; ++i){
        int task = i*256 + t;
        int n4 = task % 24, kr = task / 24;
        size_t go = (size_t)(kt*64 + kr)*H + (ncol0 + n4*4);
        float4 b = *(const float4*)(wdp + go);
        int rb = n4*4;
        Bs[(rb+0)*LDB + kr] = f2bf(b.x);
        Bs[(rb+1)*LDB + kr] = f2bf(b.y);
        Bs[(rb+2)*LDB + kr] = f2bf(b.z);
        Bs[(rb+3)*LDB + kr] = f2bf(b.w);
      }
      __syncthreads();
      #pragma unroll
      for (int kk = 0; kk < 2; ++kk){
        bf16x8 af[4];
        #pragma unroll
        for (int mi = 0; mi < 4; ++mi){
          int row = wm*64 + mi*16 + (lane & 15);
          af[mi] = *(const bf16x8*)&As[row*LDA + (kk*4 + (lane>>4))*8];
        }
        bf16x8 fb[3];
        #pragma unroll
        for (int ni = 0; ni < 3; ++ni)
          fb[ni] = read_bfrag(Bs, (wn*3 + ni)*16 + (lane & 15), kk*4 + (lane>>4));
        #pragma unroll
        for (int ni = 0; ni < 3; ++ni)
          #pragma unroll
          for (int mi = 0; mi < 4; ++mi)
            acc[mi][ni] = MFMA_BF16(af[mi], fb[ni], acc[mi][ni]);
      }
      __syncthreads();
    }

    // fold expert: bias + routing weight
    const float* bdp = bd + (size_t)e * H;
    #pragma unroll
    for (int ni = 0; ni < 3; ++ni){
      int h = ncol0 + wn*48 + ni*16 + (lane & 15);
      float bdv = bdp[h];
      #pragma unroll
      for (int mi = 0; mi < 4; ++mi){
        #pragma unroll
        for (int r = 0; r < 4; ++r){
          int trw = trow0 + wm*64 + mi*16 + (lane >> 4)*4 + r;
          float rv = rw[trw*E + e];
          oacc[mi][ni][r] += rv * (acc[mi][ni][r] + bdv);
        }
      }
    }
  }

  const int accum = (e0 != 0);
  #pragma unroll
  for (int ni = 0; ni < 3; ++ni){
    int h = ncol0 + wn*48 + ni*16 + (lane & 15);
    #pragma unroll
    for (int mi = 0; mi < 4; ++mi){
      #pragma unroll
      for (int r = 0; r < 4; ++r){
        int trw = trow0 + wm*64 + mi*16 + (lane >> 4)*4 + r;
        size_t oi = (size_t)trw * H + h;
        float v = oacc[mi][ni][r];
        if (accum) v += out[oi];
        out[oi] = v;
      }
    }
  }
}

extern "C" void kernel_launch(void* const* d_in, const int* in_sizes, int n_in,
                              void* d_out, int out_size, void* d_ws, size_t ws_size,
                              hipStream_t stream) {
  const float* hs  = (const float*)d_in[0];
  const float* rwt = (const float*)d_in[1];
  const float* Wg  = (const float*)d_in[2];
  const float* bg  = (const float*)d_in[3];
  const float* Wu  = (const float*)d_in[4];
  const float* bu  = (const float*)d_in[5];
  const float* Wd  = (const float*)d_in[6];
  const float* bd  = (const float*)d_in[7];
  float* out = (float*)d_out;

  const size_t xbytes = (size_t)T * H * 2;   // x as bf16
  const size_t perE   = (size_t)T * D * 2;   // one expert's inter as bf16
  unsigned short* xb    = (unsigned short*)d_ws;
  unsigned short* inter = (unsigned short*)((char*)d_ws + xbytes);

  long long avail = (long long)ws_size - (long long)xbytes;
  int EC = (int)(avail / (long long)perE);
  if (EC < 1) EC = 1;
  if (EC > E) EC = E;

  cvt_kernel<<<(T*H/8 + 255)/256, 256, 0, stream>>>(hs, xb, T*H/8);

  for (int e0 = 0; e0 < E; e0 += EC){
    int ec = (E - e0 < EC) ? (E - e0) : EC;
    gateup_kernel<<<dim3(T/128, D/96, ec), 256, 0, stream>>>(xb, Wg, bg, Wu, bu, inter, e0);
    down_kernel<<<dim3(T/128, H/96), 256, 0, stream>>>(inter, Wd, bd, rwt, out, e0, ec);
  }
}

// Round 3
// 2710.900 us; speedup vs baseline: 1.1399x; 1.1399x over previous
//
#include <hip/hip_runtime.h>
#include <cstdint>

// GptOssExpertsLinear: E=16, H=D=2880, T=2048.
// out[t,h] = sum_e rw[t,e] * ( act(x@Wg[e]+bg, x@Wu[e]+bu) @ Wd[e] + bd )
// R3: software-pipelined K-loop. A via global_load_lds (double-buffered,
// XOR-swizzled source per rule #21), B reg-prefetched 1 kt ahead, raw
// s_barrier + counted vmcnt so prefetches stay in flight across barriers.
// B-writes as k-pair ds_write_b32. XCD-contiguous block swizzle for L2 reuse.

#define ALPHA 1.702f
#define LIMIT 7.0f

static constexpr int E = 16;
static constexpr int H = 2880;
static constexpr int D = 2880;
static constexpr int T = 2048;
static constexpr int NKT = H / 64;   // 45 K-steps
static constexpr int LDB = 66;       // B^T row stride (shorts); 33 words == 1 mod 32

typedef float        f32x4  __attribute__((ext_vector_type(4)));
typedef short        bf16x8 __attribute__((ext_vector_type(8)));
typedef unsigned int u32x4  __attribute__((ext_vector_type(4)));

#define MFMA_BF16(a,b,c) __builtin_amdgcn_mfma_f32_16x16x32_bf16((a),(b),(c),0,0,0)
#define SBAR()        __builtin_amdgcn_s_barrier()
#define SCHED_FENCE() __builtin_amdgcn_sched_barrier(0)

__device__ __forceinline__ unsigned short f2bf(float f){
  unsigned u = __builtin_bit_cast(unsigned, f);
  u += 0x7fffu + ((u >> 16) & 1u);
  return (unsigned short)(u >> 16);
}
__device__ __forceinline__ unsigned pack2(float a, float b){
  return (unsigned)f2bf(a) | ((unsigned)f2bf(b) << 16);
}

__device__ __forceinline__ void gload_lds16(const void* g, void* l){
  __builtin_amdgcn_global_load_lds((const __attribute__((address_space(1))) unsigned*)g,
                                   (__attribute__((address_space(3))) unsigned*)l,
                                   16, 0, 0);
}

// x fp32 -> bf16, 8 elems/thread
__global__ void cvt_kernel(const float* __restrict__ in, unsigned short* __restrict__ ob, int n8){
  int i = blockIdx.x * 256 + threadIdx.x;
  if (i < n8){
    float4 a = ((const float4*)in)[2*i];
    float4 b = ((const float4*)in)[2*i+1];
    uint4 o;
    o.x = pack2(a.x, a.y); o.y = pack2(a.z, a.w);
    o.z = pack2(b.x, b.y); o.w = pack2(b.z, b.w);
    ((uint4*)ob)[i] = o;
  }
}

// one MFMA B fragment (8 bf16 along k) from the B^T tile (4B-aligned rows)
__device__ __forceinline__ bf16x8 read_bfrag(const short* Bs, int row, int c){
  const unsigned* p = (const unsigned*)&Bs[row*LDB + c*8];
  u32x4 u; u[0]=p[0]; u[1]=p[1]; u[2]=p[2]; u[3]=p[3];
  return __builtin_bit_cast(bf16x8, u);
}

// ---------------- gate+up fused GEMM + activation ----------------
// grid (16, 30, ec); block 256 = 4 waves (2m x 2n); wave tile 64x48.
__global__ __launch_bounds__(256, 2) void gateup_kernel(
    const unsigned short* __restrict__ xb,   // [T][H] bf16
    const float* __restrict__ Wg, const float* __restrict__ bg,
    const float* __restrict__ Wu, const float* __restrict__ bu,
    unsigned short* __restrict__ inter,      // [ec][T][D] bf16
    int e0)
{
  __shared__ short As[2][128*64];   // 2 x 16KB, XOR-chunk-swizzled via source
  __shared__ short Bgs[96*LDB];     // 12.4KB B^T gate
  __shared__ short Bus[96*LDB];     // 12.4KB B^T up

  const int t = threadIdx.x, lane = t & 63, wv = t >> 6;
  const int wm = wv >> 1, wn = wv & 1;

  // XCD-contiguous remap: launch-linear %8 = XCD; x-fastest within an XCD so
  // the 16 t-blocks sharing one weight panel hit the same L2.
  int nbx = gridDim.x, nby = gridDim.y;
  int lin = blockIdx.x + nbx*(blockIdx.y + nby*blockIdx.z);
  int per = (nbx*nby*gridDim.z) >> 3;
  int id2 = (lin & 7)*per + (lin >> 3);
  int bx = id2 % nbx; int rem = id2 / nbx;
  int by = rem % nby; int bz = rem / nby;

  const int trow0 = bx * 128, ncol0 = by * 96, ez = bz, e = e0 + ez;
  const float* wgp = Wg + (size_t)e * H * D;
  const float* wup = Wu + (size_t)e * H * D;

  f32x4 accg[4][3], accu[4][3];
  #pragma unroll
  for (int i = 0; i < 4; ++i)
    #pragma unroll
    for (int j = 0; j < 3; ++j){
      accg[i][j] = (f32x4){0.f,0.f,0.f,0.f};
      accu[i][j] = (f32x4){0.f,0.f,0.f,0.f};
    }

  // B staging tasks: 3 per thread, each = (n-quad, k-pair), 2 float4 per matrix
  int n4_[3], kr2_[3];
  #pragma unroll
  for (int j = 0; j < 3; ++j){ int task = j*256 + t; n4_[j] = task % 24; kr2_[j] = task / 24; }

  f32x4 pg[3][2], pu[3][2];

  auto loadB = [&](int kt){
    #pragma unroll
    for (int j = 0; j < 3; ++j){
      const float* p = wgp + (size_t)(kt*64 + kr2_[j]*2)*D + (ncol0 + n4_[j]*4);
      pg[j][0] = *(const f32x4*)p; pg[j][1] = *(const f32x4*)(p + D);
      const float* q = wup + (size_t)(kt*64 + kr2_[j]*2)*D + (ncol0 + n4_[j]*4);
      pu[j][0] = *(const f32x4*)q; pu[j][1] = *(const f32x4*)(q + D);
    }
  };
  auto writeB = [&](){
    #pragma unroll
    for (int j = 0; j < 3; ++j){
      int rb = n4_[j]*4, kc = kr2_[j]*2;
      #pragma unroll
      for (int c = 0; c < 4; ++c){
        *(unsigned*)&Bgs[(rb+c)*LDB + kc] = pack2(pg[j][0][c], pg[j][1][c]);
        *(unsigned*)&Bus[(rb+c)*LDB + kc] = pack2(pu[j][0][c], pu[j][1][c]);
      }
    }
  };
  auto dmaA = [&](int kt, int buf){
    #pragma unroll
    for (int i = 0; i < 4; ++i){
      int task = i*256 + t, row = task >> 3, ch = task & 7, sch = ch ^ (row & 7);
      gload_lds16(xb + (size_t)(trow0 + row)*H + kt*64 + sch*8, &As[buf][task*8]);
    }
  };

  loadB(0);        // B(0) -> regs     (12 vmem)
  dmaA(0, 0);      // A(0) -> LDS buf0 (4 vmem)

  for (int kt = 0; kt < NKT; ++kt){
    int cur = kt & 1, nxt = cur ^ 1;
    int ktn = (kt+1 < NKT) ? kt+1 : kt;      // clamped prefetch keeps vmcnt static
    writeB();                                // cvt+write B(kt); compiler drains B loads
    loadB(ktn);                              // prefetch B(kt+1) (in flight over compute)
    dmaA(ktn, nxt);                          // prefetch A(kt+1) (in flight over compute)
    // drain only the 4 prev-iter A-dma entries (leave 16 prefetches in flight)
    asm volatile("s_waitcnt vmcnt(16) lgkmcnt(0)" ::: "memory");
    SCHED_FENCE(); SBAR(); SCHED_FENCE();
    #pragma unroll
    for (int kk = 0; kk < 2; ++kk){
      bf16x8 af[4];
      #pragma unroll
      for (int mi = 0; mi < 4; ++mi){
        int row = wm*64 + mi*16 + (lane & 15);
        int pc  = (kk*4 + (lane>>4)) ^ (row & 7);
        af[mi] = *(const bf16x8*)&As[cur][row*64 + pc*8];
      }
      bf16x8 fgv[3], fuv[3];
      #pragma unroll
      for (int ni = 0; ni < 3; ++ni){
        int row = (wn*3 + ni)*16 + (lane & 15), c = kk*4 + (lane>>4);
        fgv[ni] = read_bfrag(Bgs, row, c);
        fuv[ni] = read_bfrag(Bus, row, c);
      }
      #pragma unroll
      for (int ni = 0; ni < 3; ++ni)
        #pragma unroll
        for (int mi = 0; mi < 4; ++mi){
          accg[mi][ni] = MFMA_BF16(af[mi], fgv[ni], accg[mi][ni]);
          accu[mi][ni] = MFMA_BF16(af[mi], fuv[ni], accu[mi][ni]);
        }
    }
    SBAR();
  }

  // epilogue: bias + clamp + glu -> inter bf16
  const float* bgp = bg + (size_t)e * D;
  const float* bup = bu + (size_t)e * D;
  unsigned short* ip = inter + (size_t)ez * T * D;
  #pragma unroll
  for (int ni = 0; ni < 3; ++ni){
    int d = ncol0 + wn*48 + ni*16 + (lane & 15);
    float bgv = bgp[d], buv = bup[d];
    #pragma unroll
    for (int mi = 0; mi < 4; ++mi){
      #pragma unroll
      for (int r = 0; r < 4; ++r){
        int trw = trow0 + wm*64 + mi*16 + (lane >> 4)*4 + r;
        float g = accg[mi][ni][r] + bgv;
        float u = accu[mi][ni][r] + buv;
        g = fminf(g, LIMIT);
        u = fminf(fmaxf(u, -LIMIT), LIMIT);
        float glu = g / (1.f + __expf(-ALPHA * g));
        ip[(size_t)trw * D + d] = f2bf((u + 1.f) * glu);
      }
    }
  }
}

// ---------------- down GEMM + routing-weighted accumulate ----------------
// grid (16, 30); block loops over ec experts; out tile owned exclusively.
__global__ __launch_bounds__(256, 2) void down_kernel(
    const unsigned short* __restrict__ inter, // [ec][T][D] bf16
    const float* __restrict__ Wd, const float* __restrict__ bd,
    const float* __restrict__ rw,             // [T][E]
    float* __restrict__ out,                  // [T][H]
    int e0, int ec)
{
  __shared__ short As[2][128*64];
  __shared__ short Bs[96*LDB];

  const int t = threadIdx.x, lane = t & 63, wv = t >> 6;
  const int wm = wv >> 1, wn = wv & 1;

  int nbx = gridDim.x, nby = gridDim.y;
  int lin = blockIdx.x + nbx*blockIdx.y;
  int per = (nbx*nby) >> 3;
  int id2 = (lin & 7)*per + (lin >> 3);
  int bx = id2 % nbx;
  int by = id2 / nbx;

  const int trow0 = bx * 128, ncol0 = by * 96;

  f32x4 oacc[4][3];
  #pragma unroll
  for (int i = 0; i < 4; ++i)
    #pragma unroll
    for (int j = 0; j < 3; ++j) oacc[i][j] = (f32x4){0.f,0.f,0.f,0.f};

  int n4_[3], kr2_[3];
  #pragma unroll
  for (int j = 0; j < 3; ++j){ int task = j*256 + t; n4_[j] = task % 24; kr2_[j] = task / 24; }

  f32x4 pb[3][2];

  auto loadB = [&](int ee, int kt){
    const float* wdp = Wd + (size_t)(e0 + ee) * D * H;
    #pragma unroll
    for (int j = 0; j < 3; ++j){
      const float* p = wdp + (size_t)(kt*64 + kr2_[j]*2)*H + (ncol0 + n4_[j]*4);
      pb[j][0] = *(const f32x4*)p; pb[j][1] = *(const f32x4*)(p + H);
    }
  };
  auto writeB = [&](){
    #pragma unroll
    for (int j = 0; j < 3; ++j){
      int rb = n4_[j]*4, kc = kr2_[j]*2;
      #pragma unroll
      for (int c = 0; c < 4; ++c)
        *(unsigned*)&Bs[(rb+c)*LDB + kc] = pack2(pb[j][0][c], pb[j][1][c]);
    }
  };
  auto dmaA = [&](int ee, int kt, int buf){
    const unsigned short* ap = inter + (size_t)ee * T * D;
    #pragma unroll
    for (int i = 0; i < 4; ++i){
      int task = i*256 + t, row = task >> 3, ch = task & 7, sch = ch ^ (row & 7);
      gload_lds16(ap + (size_t)(trow0 + row)*D + kt*64 + sch*8, &As[buf][task*8]);
    }
  };

  loadB(0, 0);     // 6 vmem
  dmaA(0, 0, 0);   // 4 vmem

  int gkt = 0;
  for (int ee = 0; ee < ec; ++ee){
    const int e = e0 + ee;
    f32x4 acc[4][3];
    #pragma unroll
    for (int i = 0; i < 4; ++i)
      #pragma unroll
      for (int j = 0; j < 3; ++j) acc[i][j] = (f32x4){0.f,0.f,0.f,0.f};

    for (int kt = 0; kt < NKT; ++kt, ++gkt){
      int cur = gkt & 1, nxt = cur ^ 1;
      int eeN, ktN;
      if (kt+1 < NKT)      { eeN = ee;   ktN = kt+1; }
      else if (ee+1 < ec)  { eeN = ee+1; ktN = 0;    }
      else                 { eeN = ee;   ktN = kt;   } // clamp at very end
      writeB();
      loadB(eeN, ktN);
      dmaA(eeN, ktN, nxt);
      asm volatile("s_waitcnt vmcnt(10) lgkmcnt(0)" ::: "memory");
      SCHED_FENCE(); SBAR(); SCHED_FENCE();
      #pragma unroll
      for (int kk = 0; kk < 2; ++kk){
        bf16x8 af[4];
        #pragma unroll
        for (int mi = 0; mi < 4; ++mi){
          int row = wm*64 + mi*16 + (lane & 15);
          int pc  = (kk*4 + (lane>>4)) ^ (row & 7);
          af[mi] = *(const bf16x8*)&As[cur][row*64 + pc*8];
        }
        bf16x8 fb[3];
        #pragma unroll
        for (int ni = 0; ni < 3; ++ni)
          fb[ni] = read_bfrag(Bs, (wn*3 + ni)*16 + (lane & 15), kk*4 + (lane>>4));
        #pragma unroll
        for (int ni = 0; ni < 3; ++ni)
          #pragma unroll
          for (int mi = 0; mi < 4; ++mi)
            acc[mi][ni] = MFMA_BF16(af[mi], fb[ni], acc[mi][ni]);
      }
      SBAR();
    }

    // fold expert: bias + routing weight
    const float* bdp = bd + (size_t)e * H;
    #pragma unroll
    for (int ni = 0; ni < 3; ++ni){
      int h = ncol0 + wn*48 + ni*16 + (lane & 15);
      float bdv = bdp[h];
      #pragma unroll
      for (int mi = 0; mi < 4; ++mi){
        #pragma unroll
        for (int r = 0; r < 4; ++r){
          int trw = trow0 + wm*64 + mi*16 + (lane >> 4)*4 + r;
          float rv = rw[trw*E + e];
          oacc[mi][ni][r] += rv * (acc[mi][ni][r] + bdv);
        }
      }
    }
  }

  const int accum = (e0 != 0);
  #pragma unroll
  for (int ni = 0; ni < 3; ++ni){
    int h = ncol0 + wn*48 + ni*16 + (lane & 15);
    #pragma unroll
    for (int mi = 0; mi < 4; ++mi){
      #pragma unroll
      for (int r = 0; r < 4; ++r){
        int trw = trow0 + wm*64 + mi*16 + (lane >> 4)*4 + r;
        size_t oi = (size_t)trw * H + h;
        float v = oacc[mi][ni][r];
        if (accum) v += out[oi];
        out[oi] = v;
      }
    }
  }
}

extern "C" void kernel_launch(void* const* d_in, const int* in_sizes, int n_in,
                              void* d_out, int out_size, void* d_ws, size_t ws_size,
                              hipStream_t stream) {
  const float* hs  = (const float*)d_in[0];
  const float* rwt = (const float*)d_in[1];
  const float* Wg  = (const float*)d_in[2];
  const float* bg  = (const float*)d_in[3];
  const float* Wu  = (const float*)d_in[4];
  const float* bu  = (const float*)d_in[5];
  const float* Wd  = (const float*)d_in[6];
  const float* bd  = (const float*)d_in[7];
  float* out = (float*)d_out;

  const size_t xbytes = (size_t)T * H * 2;
  const size_t perE   = (size_t)T * D * 2;
  unsigned short* xb    = (unsigned short*)d_ws;
  unsigned short* inter = (unsigned short*)((char*)d_ws + xbytes);

  long long avail = (long long)ws_size - (long long)xbytes;
  int EC = (int)(avail / (long long)perE);
  if (EC < 1) EC = 1;
  if (EC > E) EC = E;

  cvt_kernel<<<(T*H/8 + 255)/256, 256, 0, stream>>>(hs, xb, T*H/8);

  for (int e0 = 0; e0 < E; e0 += EC){
    int ec = (E - e0 < EC) ? (E - e0) : EC;
    gateup_kernel<<<dim3(T/128, D/96, ec), 256, 0, stream>>>(xb, Wg, bg, Wu, bu, inter, e0);
    down_kernel<<<dim3(T/128, H/96), 256, 0, stream>>>(inter, Wd, bd, rwt, out, e0, ec);
  }
}

// Round 4
// 2283.296 us; speedup vs baseline: 1.3533x; 1.1873x over previous
//
#include <hip/hip_runtime.h>
#include <cstdint>

// GptOssExpertsLinear: E=16, H=D=2880, T=2048.
// out[t,h] = sum_e rw[t,e] * ( act(x@Wg[e]+bg, x@Wu[e]+bu) @ Wd[e] + bd )
// R4: weights pre-converted+transposed to bf16 (once, memory-bound tcvt kernel)
// so GEMM B-path == A-path: global_load_lds DMA, double-buffered, XOR-swizzled
// source, b128 LDS reads. GEMM inner loop: DMA + ds_read_b128 + MFMA only.

#define ALPHA 1.702f
#define LIMIT 7.0f

static constexpr int E = 16;
static constexpr int H = 2880;
static constexpr int D = 2880;
static constexpr int T = 2048;
static constexpr int NKT = H / 64;   // 45 K-steps (K=2880 both GEMMs)

typedef float        f32x4  __attribute__((ext_vector_type(4)));
typedef short        bf16x8 __attribute__((ext_vector_type(8)));

#define MFMA_BF16(a,b,c) __builtin_amdgcn_mfma_f32_16x16x32_bf16((a),(b),(c),0,0,0)
#define SBAR()        __builtin_amdgcn_s_barrier()
#define SCHED_FENCE() __builtin_amdgcn_sched_barrier(0)

__device__ __forceinline__ unsigned short f2bf(float f){
  unsigned u = __builtin_bit_cast(unsigned, f);
  u += 0x7fffu + ((u >> 16) & 1u);
  return (unsigned short)(u >> 16);
}
__device__ __forceinline__ unsigned pack2(float a, float b){
  return (unsigned)f2bf(a) | ((unsigned)f2bf(b) << 16);
}

__device__ __forceinline__ void gload_lds16(const void* g, void* l){
  __builtin_amdgcn_global_load_lds((const __attribute__((address_space(1))) unsigned*)g,
                                   (__attribute__((address_space(3))) unsigned*)l,
                                   16, 0, 0);
}

// x fp32 -> bf16, 8 elems/thread
__global__ void cvt_kernel(const float* __restrict__ in, unsigned short* __restrict__ ob, int n8){
  int i = blockIdx.x * 256 + threadIdx.x;
  if (i < n8){
    float4 a = ((const float4*)in)[2*i];
    float4 b = ((const float4*)in)[2*i+1];
    uint4 o;
    o.x = pack2(a.x, a.y); o.y = pack2(a.z, a.w);
    o.z = pack2(b.x, b.y); o.w = pack2(b.z, b.w);
    ((uint4*)ob)[i] = o;
  }
}

// W[2880][2880] fp32 -> W^T[2880][2880] bf16, 64x64 tiles via LDS.
// grid (45, 45, nmat); z selects matrix (stride 2880*2880 on both sides).
__global__ __launch_bounds__(256) void tcvt_kernel(
    const float* __restrict__ src, unsigned short* __restrict__ dst)
{
  __shared__ unsigned short tl[64*72];   // [col][row], stride 72 shorts
  const int t = threadIdx.x;
  const size_t mo = (size_t)blockIdx.z * H * D;
  const int r0 = blockIdx.x * 64, c0 = blockIdx.y * 64;
  const float* s = src + mo;
  unsigned short* o = dst + mo;

  int rr = t >> 2;                 // 0..63
  #pragma unroll
  for (int p = 0; p < 4; ++p){
    int cc = ((t & 3) + p*4) * 4;  // 0..60 step 4
    float4 v = *(const float4*)(s + (size_t)(r0 + rr)*D + c0 + cc);
    tl[(cc+0)*72 + rr] = f2bf(v.x);
    tl[(cc+1)*72 + rr] = f2bf(v.y);
    tl[(cc+2)*72 + rr] = f2bf(v.z);
    tl[(cc+3)*72 + rr] = f2bf(v.w);
  }
  __syncthreads();
  #pragma unroll
  for (int p = 0; p < 2; ++p){
    int task = p*256 + t;          // 0..511
    int cl = task >> 3, ch = task & 7;
    bf16x8 v = *(const bf16x8*)&tl[cl*72 + ch*8];
    *(bf16x8*)(o + (size_t)(c0 + cl)*H + r0 + ch*8) = v;
  }
}

// ---------------- gate+up fused GEMM + activation ----------------
// grid (16, 30, ec); block 256 = 4 waves (2m x 2n); wave tile 64x48.
// A[128x64] + Bg[96x64] + Bu[96x64], all DMA'd, double-buffered (80KB LDS).
__global__ __launch_bounds__(256, 2) void gateup_kernel(
    const unsigned short* __restrict__ xb,    // [T][H] bf16
    const unsigned short* __restrict__ wgT,   // [ec][D][H] bf16 (n-major)
    const float* __restrict__ bg,
    const unsigned short* __restrict__ wuT,   // [ec][D][H] bf16
    const float* __restrict__ bu,
    unsigned short* __restrict__ inter,       // [ec][T][D] bf16
    int e0)
{
  __shared__ short As[2][128*64];   // 32KB
  __shared__ short Bg[2][96*64];    // 24KB
  __shared__ short Bu[2][96*64];    // 24KB  => 80KB total (2 blocks = 160KB exact)

  const int t = threadIdx.x, lane = t & 63, wv = t >> 6;
  const int wm = wv >> 1, wn = wv & 1;

  // XCD-contiguous remap (grid 480*ec, divisible by 8)
  int nbx = gridDim.x, nby = gridDim.y;
  int lin = blockIdx.x + nbx*(blockIdx.y + nby*blockIdx.z);
  int per = (nbx*nby*gridDim.z) >> 3;
  int id2 = (lin & 7)*per + (lin >> 3);
  int bx = id2 % nbx; int rem = id2 / nbx;
  int by = rem % nby; int bz = rem / nby;

  const int trow0 = bx * 128, ncol0 = by * 96, ez = bz, e = e0 + ez;
  const unsigned short* wg = wgT + (size_t)ez * D * H;
  const unsigned short* wu = wuT + (size_t)ez * D * H;

  f32x4 accg[4][3], accu[4][3];
  #pragma unroll
  for (int i = 0; i < 4; ++i)
    #pragma unroll
    for (int j = 0; j < 3; ++j){
      accg[i][j] = (f32x4){0.f,0.f,0.f,0.f};
      accu[i][j] = (f32x4){0.f,0.f,0.f,0.f};
    }

  auto stage = [&](int kt, int buf){
    // A: 1024 tasks of 16B (4/thread)
    #pragma unroll
    for (int i = 0; i < 4; ++i){
      int task = i*256 + t, row = task >> 3, ch = task & 7, sch = ch ^ (row & 7);
      gload_lds16(xb + (size_t)(trow0 + row)*H + kt*64 + sch*8, &As[buf][task*8]);
    }
    // B: 768 tasks each (3/thread per matrix)
    #pragma unroll
    for (int j = 0; j < 3; ++j){
      int task = j*256 + t, row = task >> 3, ch = task & 7, sch = ch ^ (row & 7);
      size_t go = (size_t)(ncol0 + row)*H + kt*64 + sch*8;
      gload_lds16(wg + go, &Bg[buf][task*8]);
      gload_lds16(wu + go, &Bu[buf][task*8]);
    }
  };

  stage(0, 0);   // 10 vmem in flight

  for (int kt = 0; kt < NKT; ++kt){
    int cur = kt & 1, nxt = cur ^ 1;
    int ktn = (kt+1 < NKT) ? kt+1 : kt;   // clamped keeps vmcnt static
    stage(ktn, nxt);                      // 10 more (20 outstanding)
    asm volatile("s_waitcnt vmcnt(10)" ::: "memory");  // stage(kt) landed
    SCHED_FENCE(); SBAR(); SCHED_FENCE();
    #pragma unroll
    for (int kk = 0; kk < 2; ++kk){
      bf16x8 af[4];
      #pragma unroll
      for (int mi = 0; mi < 4; ++mi){
        int row = wm*64 + mi*16 + (lane & 15);
        int pc  = (kk*4 + (lane>>4)) ^ (row & 7);
        af[mi] = *(const bf16x8*)&As[cur][row*64 + pc*8];
      }
      bf16x8 fgv[3], fuv[3];
      #pragma unroll
      for (int ni = 0; ni < 3; ++ni){
        int row = (wn*3 + ni)*16 + (lane & 15);
        int pc  = (kk*4 + (lane>>4)) ^ (row & 7);
        fgv[ni] = *(const bf16x8*)&Bg[cur][row*64 + pc*8];
        fuv[ni] = *(const bf16x8*)&Bu[cur][row*64 + pc*8];
      }
      #pragma unroll
      for (int ni = 0; ni < 3; ++ni)
        #pragma unroll
        for (int mi = 0; mi < 4; ++mi){
          accg[mi][ni] = MFMA_BF16(af[mi], fgv[ni], accg[mi][ni]);
          accu[mi][ni] = MFMA_BF16(af[mi], fuv[ni], accu[mi][ni]);
        }
    }
    SBAR();
  }
  asm volatile("s_waitcnt vmcnt(0)" ::: "memory");  // drain dummy stage before exit

  // epilogue: bias + clamp + glu -> inter bf16
  const float* bgp = bg + (size_t)e * D;
  const float* bup = bu + (size_t)e * D;
  unsigned short* ip = inter + (size_t)ez * T * D;
  #pragma unroll
  for (int ni = 0; ni < 3; ++ni){
    int d = ncol0 + wn*48 + ni*16 + (lane & 15);
    float bgv = bgp[d], buv = bup[d];
    #pragma unroll
    for (int mi = 0; mi < 4; ++mi){
      #pragma unroll
      for (int r = 0; r < 4; ++r){
        int trw = trow0 + wm*64 + mi*16 + (lane >> 4)*4 + r;
        float g = accg[mi][ni][r] + bgv;
        float u = accu[mi][ni][r] + buv;
        g = fminf(g, LIMIT);
        u = fminf(fmaxf(u, -LIMIT), LIMIT);
        float glu = g / (1.f + __expf(-ALPHA * g));
        ip[(size_t)trw * D + d] = f2bf((u + 1.f) * glu);
      }
    }
  }
}

// ---------------- down GEMM + routing-weighted accumulate ----------------
// grid (16, 30); block loops over ec experts; out tile owned exclusively.
__global__ __launch_bounds__(256, 2) void down_kernel(
    const unsigned short* __restrict__ inter, // [ec][T][D] bf16
    const unsigned short* __restrict__ wdT,   // [ec][H][D] bf16 (n-major)
    const float* __restrict__ bd,
    const float* __restrict__ rw,             // [T][E]
    float* __restrict__ out,                  // [T][H]
    int e0, int ec)
{
  __shared__ short As[2][128*64];   // 32KB
  __shared__ short Bs[2][96*64];    // 24KB => 56KB

  const int t = threadIdx.x, lane = t & 63, wv = t >> 6;
  const int wm = wv >> 1, wn = wv & 1;

  int nbx = gridDim.x, nby = gridDim.y;
  int lin = blockIdx.x + nbx*blockIdx.y;
  int per = (nbx*nby) >> 3;
  int id2 = (lin & 7)*per + (lin >> 3);
  int bx = id2 % nbx;
  int by = id2 / nbx;

  const int trow0 = bx * 128, ncol0 = by * 96;

  f32x4 oacc[4][3];
  #pragma unroll
  for (int i = 0; i < 4; ++i)
    #pragma unroll
    for (int j = 0; j < 3; ++j) oacc[i][j] = (f32x4){0.f,0.f,0.f,0.f};

  auto stage = [&](int ee, int kt, int buf){
    const unsigned short* ap = inter + (size_t)ee * T * D;
    const unsigned short* wd = wdT + (size_t)ee * H * D;
    #pragma unroll
    for (int i = 0; i < 4; ++i){
      int task = i*256 + t, row = task >> 3, ch = task & 7, sch = ch ^ (row & 7);
      gload_lds16(ap + (size_t)(trow0 + row)*D + kt*64 + sch*8, &As[buf][task*8]);
    }
    #pragma unroll
    for (int j = 0; j < 3; ++j){
      int task = j*256 + t, row = task >> 3, ch = task & 7, sch = ch ^ (row & 7);
      gload_lds16(wd + (size_t)(ncol0 + row)*D + kt*64 + sch*8, &Bs[buf][task*8]);
    }
  };

  stage(0, 0, 0);   // 7 vmem

  int gkt = 0;
  for (int ee = 0; ee < ec; ++ee){
    const int e = e0 + ee;
    f32x4 acc[4][3];
    #pragma unroll
    for (int i = 0; i < 4; ++i)
      #pragma unroll
      for (int j = 0; j < 3; ++j) acc[i][j] = (f32x4){0.f,0.f,0.f,0.f};

    for (int kt = 0; kt < NKT; ++kt, ++gkt){
      int cur = gkt & 1, nxt = cur ^ 1;
      int eeN, ktN;
      if (kt+1 < NKT)      { eeN = ee;   ktN = kt+1; }
      else if (ee+1 < ec)  { eeN = ee+1; ktN = 0;    }
      else                 { eeN = ee;   ktN = kt;   }
      stage(eeN, ktN, nxt);
      asm volatile("s_waitcnt vmcnt(7)" ::: "memory");
      SCHED_FENCE(); SBAR(); SCHED_FENCE();
      #pragma unroll
      for (int kk = 0; kk < 2; ++kk){
        bf16x8 af[4];
        #pragma unroll
        for (int mi = 0; mi < 4; ++mi){
          int row = wm*64 + mi*16 + (lane & 15);
          int pc  = (kk*4 + (lane>>4)) ^ (row & 7);
          af[mi] = *(const bf16x8*)&As[cur][row*64 + pc*8];
        }
        bf16x8 fb[3];
        #pragma unroll
        for (int ni = 0; ni < 3; ++ni){
          int row = (wn*3 + ni)*16 + (lane & 15);
          int pc  = (kk*4 + (lane>>4)) ^ (row & 7);
          fb[ni] = *(const bf16x8*)&Bs[cur][row*64 + pc*8];
        }
        #pragma unroll
        for (int ni = 0; ni < 3; ++ni)
          #pragma unroll
          for (int mi = 0; mi < 4; ++mi)
            acc[mi][ni] = MFMA_BF16(af[mi], fb[ni], acc[mi][ni]);
      }
      SBAR();
    }

    // fold expert: bias + routing weight
    const float* bdp = bd + (size_t)e * H;
    #pragma unroll
    for (int ni = 0; ni < 3; ++ni){
      int h = ncol0 + wn*48 + ni*16 + (lane & 15);
      float bdv = bdp[h];
      #pragma unroll
      for (int mi = 0; mi < 4; ++mi){
        #pragma unroll
        for (int r = 0; r < 4; ++r){
          int trw = trow0 + wm*64 + mi*16 + (lane >> 4)*4 + r;
          float rv = rw[trw*E + e];
          oacc[mi][ni][r] += rv * (acc[mi][ni][r] + bdv);
        }
      }
    }
  }
  asm volatile("s_waitcnt vmcnt(0)" ::: "memory");

  const int accum = (e0 != 0);
  #pragma unroll
  for (int ni = 0; ni < 3; ++ni){
    int h = ncol0 + wn*48 + ni*16 + (lane & 15);
    #pragma unroll
    for (int mi = 0; mi < 4; ++mi){
      #pragma unroll
      for (int r = 0; r < 4; ++r){
        int trw = trow0 + wm*64 + mi*16 + (lane >> 4)*4 + r;
        size_t oi = (size_t)trw * H + h;
        float v = oacc[mi][ni][r];
        if (accum) v += out[oi];
        out[oi] = v;
      }
    }
  }
}

extern "C" void kernel_launch(void* const* d_in, const int* in_sizes, int n_in,
                              void* d_out, int out_size, void* d_ws, size_t ws_size,
                              hipStream_t stream) {
  const float* hs  = (const float*)d_in[0];
  const float* rwt = (const float*)d_in[1];
  const float* Wg  = (const float*)d_in[2];
  const float* bg  = (const float*)d_in[3];
  const float* Wu  = (const float*)d_in[4];
  const float* bu  = (const float*)d_in[5];
  const float* Wd  = (const float*)d_in[6];
  const float* bd  = (const float*)d_in[7];
  float* out = (float*)d_out;

  const size_t xbytes = (size_t)T * H * 2;                 // 11.8 MB
  const size_t interB = (size_t)T * D * 2;                 // 11.8 MB / expert
  const size_t wB     = (size_t)H * D * 2;                 // 16.6 MB / expert / matrix
  const size_t perE   = interB + 2*wB;                     // ~45 MB / expert

  long long avail = (long long)ws_size - (long long)xbytes;
  int EC = (int)(avail / (long long)perE);
  if (EC < 1) EC = 1;
  if (EC > E) EC = E;

  unsigned short* xb    = (unsigned short*)d_ws;
  unsigned short* inter = (unsigned short*)((char*)d_ws + xbytes);
  unsigned short* wgT   = (unsigned short*)((char*)d_ws + xbytes + (size_t)EC*interB);
  unsigned short* wuT   = wgT + (size_t)EC * H * D;
  unsigned short* wdT   = wgT;   // aliases wgT (stream-serialized reuse)

  cvt_kernel<<<(T*H/8 + 255)/256, 256, 0, stream>>>(hs, xb, T*H/8);

  for (int e0 = 0; e0 < E; e0 += EC){
    int ec = (E - e0 < EC) ? (E - e0) : EC;
    tcvt_kernel<<<dim3(45,45,ec), 256, 0, stream>>>(Wg + (size_t)e0*H*D, wgT);
    tcvt_kernel<<<dim3(45,45,ec), 256, 0, stream>>>(Wu + (size_t)e0*H*D, wuT);
    gateup_kernel<<<dim3(T/128, D/96, ec), 256, 0, stream>>>(xb, wgT, bg, wuT, bu, inter, e0);
    tcvt_kernel<<<dim3(45,45,ec), 256, 0, stream>>>(Wd + (size_t)e0*D*H, wdT);
    down_kernel<<<dim3(T/128, H/96), 256, 0, stream>>>(inter, wdT, bd, rwt, out, e0, ec);
  }
}

// Round 5
// 2264.704 us; speedup vs baseline: 1.3644x; 1.0082x over previous
//
#include <hip/hip_runtime.h>
#include <cstdint>

// GptOssExpertsLinear: E=16, H=D=2880, T=2048.
// out[t,h] = sum_e rw[t,e] * ( act(x@Wg[e]+bg, x@Wu[e]+bu) @ Wd[e] + bd )
// R5: down widened to 128x192 tiles (wave 64x96, gateup-parity MFMA/LDS ratio),
// 4 expert-groups in grid.z writing fp32 partials, + reduce kernel.
// Weights pre-transposed+converted to bf16 by tcvt (once), GEMMs are pure
// DMA(global_load_lds, XOR-swizzled source) + ds_read_b128 + MFMA.

#define ALPHA 1.702f
#define LIMIT 7.0f

static constexpr int E = 16;
static constexpr int H = 2880;
static constexpr int D = 2880;
static constexpr int T = 2048;
static constexpr int NKT = H / 64;   // 45 K-steps (K=2880 both GEMMs)
static constexpr int NG  = 4;        // down expert groups (partial buffers)

typedef float        f32x4  __attribute__((ext_vector_type(4)));
typedef short        bf16x8 __attribute__((ext_vector_type(8)));

#define MFMA_BF16(a,b,c) __builtin_amdgcn_mfma_f32_16x16x32_bf16((a),(b),(c),0,0,0)
#define SBAR()        __builtin_amdgcn_s_barrier()
#define SCHED_FENCE() __builtin_amdgcn_sched_barrier(0)

__device__ __forceinline__ unsigned short f2bf(float f){
  unsigned u = __builtin_bit_cast(unsigned, f);
  u += 0x7fffu + ((u >> 16) & 1u);
  return (unsigned short)(u >> 16);
}
__device__ __forceinline__ unsigned pack2(float a, float b){
  return (unsigned)f2bf(a) | ((unsigned)f2bf(b) << 16);
}

__device__ __forceinline__ void gload_lds16(const void* g, void* l){
  __builtin_amdgcn_global_load_lds((const __attribute__((address_space(1))) unsigned*)g,
                                   (__attribute__((address_space(3))) unsigned*)l,
                                   16, 0, 0);
}

// x fp32 -> bf16, 8 elems/thread
__global__ void cvt_kernel(const float* __restrict__ in, unsigned short* __restrict__ ob, int n8){
  int i = blockIdx.x * 256 + threadIdx.x;
  if (i < n8){
    float4 a = ((const float4*)in)[2*i];
    float4 b = ((const float4*)in)[2*i+1];
    uint4 o;
    o.x = pack2(a.x, a.y); o.y = pack2(a.z, a.w);
    o.z = pack2(b.x, b.y); o.w = pack2(b.z, b.w);
    ((uint4*)ob)[i] = o;
  }
}

// W[2880][2880] fp32 -> W^T[2880][2880] bf16, 64x64 tiles via LDS.
__global__ __launch_bounds__(256) void tcvt_kernel(
    const float* __restrict__ src, unsigned short* __restrict__ dst)
{
  __shared__ unsigned short tl[64*72];
  const int t = threadIdx.x;
  const size_t mo = (size_t)blockIdx.z * H * D;
  const int r0 = blockIdx.x * 64, c0 = blockIdx.y * 64;
  const float* s = src + mo;
  unsigned short* o = dst + mo;

  int rr = t >> 2;
  #pragma unroll
  for (int p = 0; p < 4; ++p){
    int cc = ((t & 3) + p*4) * 4;
    float4 v = *(const float4*)(s + (size_t)(r0 + rr)*D + c0 + cc);
    tl[(cc+0)*72 + rr] = f2bf(v.x);
    tl[(cc+1)*72 + rr] = f2bf(v.y);
    tl[(cc+2)*72 + rr] = f2bf(v.z);
    tl[(cc+3)*72 + rr] = f2bf(v.w);
  }
  __syncthreads();
  #pragma unroll
  for (int p = 0; p < 2; ++p){
    int task = p*256 + t;
    int cl = task >> 3, ch = task & 7;
    bf16x8 v = *(const bf16x8*)&tl[cl*72 + ch*8];
    *(bf16x8*)(o + (size_t)(c0 + cl)*H + r0 + ch*8) = v;
  }
}

// sum the NG down partials -> out
__global__ void reduce_kernel(const float* __restrict__ p, float* __restrict__ out, int n4){
  int i = blockIdx.x * 256 + threadIdx.x;
  if (i < n4){
    f32x4 a = ((const f32x4*)p)[i];
    #pragma unroll
    for (int g = 1; g < NG; ++g)
      a += ((const f32x4*)(p + (size_t)g * T * H))[i];
    ((f32x4*)out)[i] = a;
  }
}

// ---------------- gate+up fused GEMM + activation ----------------
// grid (16, 30, ec); block 256 = 4 waves (2m x 2n); wave tile 64x48 (x2 mats).
__global__ __launch_bounds__(256, 2) void gateup_kernel(
    const unsigned short* __restrict__ xb,    // [T][H] bf16
    const unsigned short* __restrict__ wgT,   // [ec][D][H] bf16 (n-major)
    const float* __restrict__ bg,
    const unsigned short* __restrict__ wuT,   // [ec][D][H] bf16
    const float* __restrict__ bu,
    unsigned short* __restrict__ inter,       // [ec][T][D] bf16
    int e0)
{
  __shared__ short As[2][128*64];   // 32KB
  __shared__ short Bg[2][96*64];    // 24KB
  __shared__ short Bu[2][96*64];    // 24KB => 80KB, 2 blocks/CU

  const int t = threadIdx.x, lane = t & 63, wv = t >> 6;
  const int wm = wv >> 1, wn = wv & 1;

  int nbx = gridDim.x, nby = gridDim.y;
  int lin = blockIdx.x + nbx*(blockIdx.y + nby*blockIdx.z);
  int per = (nbx*nby*gridDim.z) >> 3;
  int id2 = (lin & 7)*per + (lin >> 3);
  int bx = id2 % nbx; int rem = id2 / nbx;
  int by = rem % nby; int bz = rem / nby;

  const int trow0 = bx * 128, ncol0 = by * 96, ez = bz, e = e0 + ez;
  const unsigned short* wg = wgT + (size_t)ez * D * H;
  const unsigned short* wu = wuT + (size_t)ez * D * H;

  f32x4 accg[4][3], accu[4][3];
  #pragma unroll
  for (int i = 0; i < 4; ++i)
    #pragma unroll
    for (int j = 0; j < 3; ++j){
      accg[i][j] = (f32x4){0.f,0.f,0.f,0.f};
      accu[i][j] = (f32x4){0.f,0.f,0.f,0.f};
    }

  auto stage = [&](int kt, int buf){
    #pragma unroll
    for (int i = 0; i < 4; ++i){
      int task = i*256 + t, row = task >> 3, ch = task & 7, sch = ch ^ (row & 7);
      gload_lds16(xb + (size_t)(trow0 + row)*H + kt*64 + sch*8, &As[buf][task*8]);
    }
    #pragma unroll
    for (int j = 0; j < 3; ++j){
      int task = j*256 + t, row = task >> 3, ch = task & 7, sch = ch ^ (row & 7);
      size_t go = (size_t)(ncol0 + row)*H + kt*64 + sch*8;
      gload_lds16(wg + go, &Bg[buf][task*8]);
      gload_lds16(wu + go, &Bu[buf][task*8]);
    }
  };

  stage(0, 0);   // 10 vmem in flight

  for (int kt = 0; kt < NKT; ++kt){
    int cur = kt & 1, nxt = cur ^ 1;
    int ktn = (kt+1 < NKT) ? kt+1 : kt;
    stage(ktn, nxt);
    asm volatile("s_waitcnt vmcnt(10)" ::: "memory");
    SCHED_FENCE(); SBAR(); SCHED_FENCE();
    #pragma unroll
    for (int kk = 0; kk < 2; ++kk){
      bf16x8 af[4];
      #pragma unroll
      for (int mi = 0; mi < 4; ++mi){
        int row = wm*64 + mi*16 + (lane & 15);
        int pc  = (kk*4 + (lane>>4)) ^ (row & 7);
        af[mi] = *(const bf16x8*)&As[cur][row*64 + pc*8];
      }
      bf16x8 fgv[3], fuv[3];
      #pragma unroll
      for (int ni = 0; ni < 3; ++ni){
        int row = (wn*3 + ni)*16 + (lane & 15);
        int pc  = (kk*4 + (lane>>4)) ^ (row & 7);
        fgv[ni] = *(const bf16x8*)&Bg[cur][row*64 + pc*8];
        fuv[ni] = *(const bf16x8*)&Bu[cur][row*64 + pc*8];
      }
      #pragma unroll
      for (int ni = 0; ni < 3; ++ni)
        #pragma unroll
        for (int mi = 0; mi < 4; ++mi){
          accg[mi][ni] = MFMA_BF16(af[mi], fgv[ni], accg[mi][ni]);
          accu[mi][ni] = MFMA_BF16(af[mi], fuv[ni], accu[mi][ni]);
        }
    }
    SBAR();
  }
  asm volatile("s_waitcnt vmcnt(0)" ::: "memory");

  const float* bgp = bg + (size_t)e * D;
  const float* bup = bu + (size_t)e * D;
  unsigned short* ip = inter + (size_t)ez * T * D;
  #pragma unroll
  for (int ni = 0; ni < 3; ++ni){
    int d = ncol0 + wn*48 + ni*16 + (lane & 15);
    float bgv = bgp[d], buv = bup[d];
    #pragma unroll
    for (int mi = 0; mi < 4; ++mi){
      #pragma unroll
      for (int r = 0; r < 4; ++r){
        int trw = trow0 + wm*64 + mi*16 + (lane >> 4)*4 + r;
        float g = accg[mi][ni][r] + bgv;
        float u = accu[mi][ni][r] + buv;
        g = fminf(g, LIMIT);
        u = fminf(fmaxf(u, -LIMIT), LIMIT);
        float glu = g / (1.f + __expf(-ALPHA * g));
        ip[(size_t)trw * D + d] = f2bf((u + 1.f) * glu);
      }
    }
  }
}

// ---------------- down GEMM + routing-weighted accumulate ----------------
// grid (16, 15, NG); tile 128x192; wave tile 64x96. Group g handles experts
// e0+g, e0+g+4, ... accumulating rw-weighted results into pout[g] (fp32).
__global__ __launch_bounds__(256, 2) void down_kernel(
    const unsigned short* __restrict__ inter, // [ec][T][D] bf16
    const unsigned short* __restrict__ wdT,   // [ec][H][D] bf16 (n-major)
    const float* __restrict__ bd,
    const float* __restrict__ rw,             // [T][E]
    float* __restrict__ pout,                 // [NG][T][H] fp32 partials
    int e0, int ec)
{
  __shared__ short As[2][128*64];   // 32KB
  __shared__ short Bs[2][192*64];   // 48KB => 80KB, 2 blocks/CU

  const int t = threadIdx.x, lane = t & 63, wv = t >> 6;
  const int wm = wv >> 1, wn = wv & 1;

  int nbx = gridDim.x, nby = gridDim.y;
  int lin = blockIdx.x + nbx*(blockIdx.y + nby*blockIdx.z);
  int per = (nbx*nby*gridDim.z) >> 3;
  int id2 = (lin & 7)*per + (lin >> 3);
  int bx = id2 % nbx; int rem = id2 / nbx;
  int by = rem % nby; int g  = rem / nby;

  const int trow0 = bx * 128, ncol0 = by * 192;
  const int ne = (ec > g) ? ((ec - 1 - g) >> 2) + 1 : 0;  // experts in this group

  f32x4 oacc[4][6];
  #pragma unroll
  for (int i = 0; i < 4; ++i)
    #pragma unroll
    for (int j = 0; j < 6; ++j) oacc[i][j] = (f32x4){0.f,0.f,0.f,0.f};

  auto stage = [&](int ee, int kt, int buf){
    const unsigned short* ap = inter + (size_t)ee * T * D;
    const unsigned short* wd = wdT + (size_t)ee * H * D;
    #pragma unroll
    for (int i = 0; i < 4; ++i){
      int task = i*256 + t, row = task >> 3, ch = task & 7, sch = ch ^ (row & 7);
      gload_lds16(ap + (size_t)(trow0 + row)*D + kt*64 + sch*8, &As[buf][task*8]);
    }
    #pragma unroll
    for (int j = 0; j < 6; ++j){
      int task = j*256 + t, row = task >> 3, ch = task & 7, sch = ch ^ (row & 7);
      gload_lds16(wd + (size_t)(ncol0 + row)*D + kt*64 + sch*8, &Bs[buf][task*8]);
    }
  };

  if (ne > 0){
    stage(g, 0, 0);   // 10 vmem

    int gkt = 0;
    for (int ei = 0; ei < ne; ++ei){
      const int ee = g + ei*4;      // local (chunk) expert index
      const int e  = e0 + ee;
      f32x4 acc[4][6];
      #pragma unroll
      for (int i = 0; i < 4; ++i)
        #pragma unroll
        for (int j = 0; j < 6; ++j) acc[i][j] = (f32x4){0.f,0.f,0.f,0.f};

      for (int kt = 0; kt < NKT; ++kt, ++gkt){
        int cur = gkt & 1, nxt = cur ^ 1;
        int eeN, ktN;
        if (kt+1 < NKT)      { eeN = ee;     ktN = kt+1; }
        else if (ei+1 < ne)  { eeN = ee + 4; ktN = 0;    }
        else                 { eeN = ee;     ktN = kt;   }
        stage(eeN, ktN, nxt);
        asm volatile("s_waitcnt vmcnt(10)" ::: "memory");
        SCHED_FENCE(); SBAR(); SCHED_FENCE();
        #pragma unroll
        for (int kk = 0; kk < 2; ++kk){
          bf16x8 af[4];
          #pragma unroll
          for (int mi = 0; mi < 4; ++mi){
            int row = wm*64 + mi*16 + (lane & 15);
            int pc  = (kk*4 + (lane>>4)) ^ (row & 7);
            af[mi] = *(const bf16x8*)&As[cur][row*64 + pc*8];
          }
          bf16x8 fb[6];
          #pragma unroll
          for (int ni = 0; ni < 6; ++ni){
            int row = wn*96 + ni*16 + (lane & 15);
            int pc  = (kk*4 + (lane>>4)) ^ (row & 7);
            fb[ni] = *(const bf16x8*)&Bs[cur][row*64 + pc*8];
          }
          #pragma unroll
          for (int ni = 0; ni < 6; ++ni)
            #pragma unroll
            for (int mi = 0; mi < 4; ++mi)
              acc[mi][ni] = MFMA_BF16(af[mi], fb[ni], acc[mi][ni]);
        }
        SBAR();
      }

      // fold expert: bias + routing weight
      const float* bdp = bd + (size_t)e * H;
      #pragma unroll
      for (int ni = 0; ni < 6; ++ni){
        int h = ncol0 + wn*96 + ni*16 + (lane & 15);
        float bdv = bdp[h];
        #pragma unroll
        for (int mi = 0; mi < 4; ++mi){
          #pragma unroll
          for (int r = 0; r < 4; ++r){
            int trw = trow0 + wm*64 + mi*16 + (lane >> 4)*4 + r;
            float rv = rw[trw*E + e];
            oacc[mi][ni][r] += rv * (acc[mi][ni][r] + bdv);
          }
        }
      }
    }
    asm volatile("s_waitcnt vmcnt(0)" ::: "memory");
  }

  // write / accumulate partial (blocks with ne==0 still init on first chunk)
  float* pp = pout + (size_t)g * T * H;
  const int accum = (e0 != 0);
  #pragma unroll
  for (int ni = 0; ni < 6; ++ni){
    int h = ncol0 + wn*96 + ni*16 + (lane & 15);
    #pragma unroll
    for (int mi = 0; mi < 4; ++mi){
      #pragma unroll
      for (int r = 0; r < 4; ++r){
        int trw = trow0 + wm*64 + mi*16 + (lane >> 4)*4 + r;
        size_t oi = (size_t)trw * H + h;
        float v = oacc[mi][ni][r];
        if (accum) v += pp[oi];
        pp[oi] = v;
      }
    }
  }
}

extern "C" void kernel_launch(void* const* d_in, const int* in_sizes, int n_in,
                              void* d_out, int out_size, void* d_ws, size_t ws_size,
                              hipStream_t stream) {
  const float* hs  = (const float*)d_in[0];
  const float* rwt = (const float*)d_in[1];
  const float* Wg  = (const float*)d_in[2];
  const float* bg  = (const float*)d_in[3];
  const float* Wu  = (const float*)d_in[4];
  const float* bu  = (const float*)d_in[5];
  const float* Wd  = (const float*)d_in[6];
  const float* bd  = (const float*)d_in[7];
  float* out = (float*)d_out;

  const size_t xbytes = (size_t)T * H * 2;          // 11.8 MB
  const size_t poutB  = (size_t)NG * T * H * 4;     // 94.4 MB
  const size_t interB = (size_t)T * D * 2;          // 11.8 MB / expert
  const size_t wB     = (size_t)H * D * 2;          // 16.6 MB / expert / matrix
  const size_t perE   = interB + 2*wB;              // ~45 MB / expert

  long long avail = (long long)ws_size - (long long)(xbytes + poutB);
  int EC = (int)(avail / (long long)perE);
  if (EC < 1) EC = 1;
  if (EC > E) EC = E;

  unsigned short* xb    = (unsigned short*)d_ws;
  float*          pout  = (float*)((char*)d_ws + xbytes);
  unsigned short* inter = (unsigned short*)((char*)d_ws + xbytes + poutB);
  unsigned short* wgT   = (unsigned short*)((char*)d_ws + xbytes + poutB + (size_t)EC*interB);
  unsigned short* wuT   = wgT + (size_t)EC * H * D;
  unsigned short* wdT   = wgT;   // aliases wgT (stream-serialized reuse)

  cvt_kernel<<<(T*H/8 + 255)/256, 256, 0, stream>>>(hs, xb, T*H/8);

  for (int e0 = 0; e0 < E; e0 += EC){
    int ec = (E - e0 < EC) ? (E - e0) : EC;
    tcvt_kernel<<<dim3(45,45,ec), 256, 0, stream>>>(Wg + (size_t)e0*H*D, wgT);
    tcvt_kernel<<<dim3(45,45,ec), 256, 0, stream>>>(Wu + (size_t)e0*H*D, wuT);
    gateup_kernel<<<dim3(T/128, D/96, ec), 256, 0, stream>>>(xb, wgT, bg, wuT, bu, inter, e0);
    tcvt_kernel<<<dim3(45,45,ec), 256, 0, stream>>>(Wd + (size_t)e0*D*H, wdT);
    down_kernel<<<dim3(T/128, H/192, NG), 256, 0, stream>>>(inter, wdT, bd, rwt, pout, e0, ec);
  }
  reduce_kernel<<<(T*H/4 + 255)/256, 256, 0, stream>>>(pout, out, T*H/4);
}